// Round 10
// baseline (162.163 us; speedup 1.0000x reference)
//
#include <hip/hip_runtime.h>

typedef __attribute__((ext_vector_type(8))) short short8;
typedef __attribute__((ext_vector_type(4))) float f32x4;

// async global->LDS, 16B per lane, dest = wave-uniform base + lane*16
#define GLOAD16(g, l)                                                        \
  __builtin_amdgcn_global_load_lds(                                          \
      (const __attribute__((address_space(1))) unsigned int*)(g),            \
      (__attribute__((address_space(3))) unsigned int*)(l), 16, 0, 0)

__device__ __forceinline__ unsigned short f2bf(float f) {
  union { float f; unsigned int u; } v;
  v.f = f;
  unsigned int u = v.u;
  u += 0x7FFFu + ((u >> 16) & 1u);  // round-to-nearest-even
  return (unsigned short)(u >> 16);
}

__device__ __forceinline__ short8 pack8(float4 a, float4 b) {
  short8 r;
  r[0] = (short)f2bf(a.x); r[1] = (short)f2bf(a.y);
  r[2] = (short)f2bf(a.z); r[3] = (short)f2bf(a.w);
  r[4] = (short)f2bf(b.x); r[5] = (short)f2bf(b.y);
  r[6] = (short)f2bf(b.z); r[7] = (short)f2bf(b.w);
  return r;
}

#define BM 128
#define BN 128
#define BK 32

// ---------- kernel 1: prep (r5-validated; r8's 4-row variant regressed) ----
__global__ __launch_bounds__(256)
void prep2_kernel(const float* __restrict__ emb, const int* __restrict__ labels,
                  const float* __restrict__ emb_mem, const int* __restrict__ lbl_mem,
                  unsigned short* __restrict__ refbf, float* __restrict__ sqb,
                  int* __restrict__ reflab, float* __restrict__ facc,
                  int* __restrict__ fcnt, int Bn, int Dn, int Mn) {
  if (blockIdx.x == 0 && threadIdx.x == 0) { *facc = 0.f; *fcnt = 0; }
  int wid = threadIdx.x >> 6, lane = threadIdx.x & 63;
  int row = blockIdx.x * 4 + wid;
  if (row >= Mn) return;
  const float* src = (row < Bn) ? (emb + (size_t)row * Dn)
                                : (emb_mem + (size_t)(row - Bn) * Dn);
  unsigned short* dst = refbf + (size_t)row * Dn;
  float s = 0.f;
  for (int c0 = lane * 8; c0 < Dn; c0 += 64 * 8) {
    float4 v0 = ((const float4*)(src + c0))[0];
    float4 v1 = ((const float4*)(src + c0))[1];
    s += v0.x * v0.x + v0.y * v0.y + v0.z * v0.z + v0.w * v0.w;
    s += v1.x * v1.x + v1.y * v1.y + v1.z * v1.z + v1.w * v1.w;
    *(short8*)(dst + c0) = pack8(v0, v1);
  }
#pragma unroll
  for (int off = 32; off; off >>= 1) s += __shfl_xor(s, off);
  if (lane == 0) {
    sqb[row] = s;
    reflab[row] = (row < Bn) ? labels[row] : lbl_mem[row - Bn];
  }
}

// ---------- kernel 2a: GEMM 128x256, single-barrier LDS double-buffer ------
// Per iter: GLOAD tile k+1 into buf^1 FIRST, compute tile k from buf, ONE
// __syncthreads. The vmcnt(0) drain at the barrier now waits on loads that
// have had the whole compute phase to land -> drain ~0 (vs r8's 2-barrier
// loop where the drain hit just-issued loads every iteration).
__global__ __launch_bounds__(256, 2)
void gemm512x2db_kernel(const unsigned short* __restrict__ refbf,
                        const float* __restrict__ sqb,
                        const int* __restrict__ reflab,
                        float* __restrict__ part) {
  // 48KB: buf0 [As 8K | Bs 16K] @0, buf1 @24576; epilogue red4 aliases 0..32K
  __shared__ __align__(16) char smem[49152];
  f32x4* red4 = (f32x4*)smem;  // [2][128][8] f32x4 (alias, used after K-loop)

  const int npart = 128;               // j-pairs
  int bid = blockIdx.x;                // 1024 blocks
  int c = bid & 7, g = bid >> 3;       // XCD-sliced (validated r3/r5)
  int jp = c * 16 + (g >> 3);          // j-pair index [0,128)
  int it = g & 7;
  int rowBase = it * BM, colBase = jp * 256;

  int tid = threadIdx.x, lane = tid & 63, w = tid >> 6;
  int wr = w >> 1, wc = w & 1;         // 2x2 waves; each 64 rows x 128 cols
  int l16 = lane & 15, quad = lane >> 4;
  int lrow = lane >> 2, lk = lane & 3;

  // A staging: wave stages rows w*32..+32 (2 GLOADs/iter)
  int ra = w * 32 + lrow;
  int caa = (lk - (ra >> 1)) & 3;      // chunk rotation: conflict-free ds_read
  const char* gA0 = (const char*)refbf + (size_t)(rowBase + ra) * 1024 + caa * 16;
  const char* gA1 = gA0 + 16 * 1024;
  // B staging: wave stages rows w*64..+64 (4 GLOADs/iter)
  int rb = w * 64 + lrow;
  int cab = (lk - (rb >> 1)) & 3;
  const char* gB0 = (const char*)refbf + (size_t)(colBase + rb) * 1024 + cab * 16;
  const char* gB1 = gB0 + 16 * 1024;
  const char* gB2 = gB0 + 32 * 1024;
  const char* gB3 = gB0 + 48 * 1024;

  char* lA[2] = {smem + w * 2048, smem + 24576 + w * 2048};
  char* lB[2] = {smem + 8192 + w * 4096, smem + 24576 + 8192 + w * 4096};

  f32x4 acc[4][8] = {};

  // preload tile 0 into buf 0
  GLOAD16(gA0, lA[0]);
  GLOAD16(gA1, lA[0] + 1024);
  GLOAD16(gB0, lB[0]);
  GLOAD16(gB1, lB[0] + 1024);
  GLOAD16(gB2, lB[0] + 2048);
  GLOAD16(gB3, lB[0] + 3072);
  __syncthreads();

#pragma unroll
  for (int kk = 0; kk < 16; ++kk) {
    int cur = kk & 1, nxt = cur ^ 1;
    if (kk < 15) {                     // prefetch tile kk+1 into the idle buf
      int ko = (kk + 1) * 64;
      GLOAD16(gA0 + ko, lA[nxt]);
      GLOAD16(gA1 + ko, lA[nxt] + 1024);
      GLOAD16(gB0 + ko, lB[nxt]);
      GLOAD16(gB1 + ko, lB[nxt] + 1024);
      GLOAD16(gB2 + ko, lB[nxt] + 2048);
      GLOAD16(gB3 + ko, lB[nxt] + 3072);
    }
    const unsigned short* Asc = (const unsigned short*)(smem + cur * 24576);
    const unsigned short* Bsc = (const unsigned short*)(smem + cur * 24576 + 8192);
    short8 af[4], bfr[8];
#pragma unroll
    for (int mi = 0; mi < 4; ++mi) {
      int row = wr * 64 + mi * 16 + l16;
      af[mi] = *(const short8*)&Asc[row * BK + ((quad + (row >> 1)) & 3) * 8];
    }
#pragma unroll
    for (int ni = 0; ni < 8; ++ni) {
      int row = wc * 128 + ni * 16 + l16;
      bfr[ni] = *(const short8*)&Bsc[row * BK + ((quad + (row >> 1)) & 3) * 8];
    }
#pragma unroll
    for (int mi = 0; mi < 4; ++mi)
#pragma unroll
      for (int ni = 0; ni < 8; ++ni)
        acc[mi][ni] = __builtin_amdgcn_mfma_f32_16x16x32_bf16(
            af[mi], bfr[ni], acc[mi][ni], 0, 0, 0);
    __syncthreads();  // single barrier: reads of cur done + nxt loads drained
  }

  // ---- epilogue (r8-validated): packed counters, 1 shfl, LDS fold --------
  float sqc[8];
  int labc[8];
#pragma unroll
  for (int ni = 0; ni < 8; ++ni) {
    int gcol = colBase + wc * 128 + ni * 16 + l16;
    sqc[ni] = sqb[gcol];
    labc[ni] = reflab[gcol];
  }
#pragma unroll
  for (int mi = 0; mi < 4; ++mi) {
    int lr0 = wr * 64 + mi * 16 + quad * 4;
#pragma unroll
    for (int r = 0; r < 4; ++r) {
      int lrl = lr0 + r;
      int grow = rowBase + lrl;
      float sqr = sqb[grow];
      int labr = reflab[grow];
      float ps = 0.f, ns = 0.f, cpk = 0.f;  // cpk = pos_cnt + 512*neg_cnt
#pragma unroll
      for (int ni = 0; ni < 8; ++ni) {
        int gcol = colBase + wc * 128 + ni * 16 + l16;
        float dist = fmaxf(sqr + sqc[ni] - 2.0f * acc[mi][ni][r], 0.f);
        bool self = (gcol == grow);  // idx_ref[j]!=i reduces to j!=i
        bool same = (labc[ni] == labr);
        if (same && !self && dist > 0.f) { ps += dist; cpk += 1.f; }
        if (!same && !self && dist < 1.f) { ns += 1.f - dist; cpk += 512.f; }
      }
      ps += __shfl_xor(ps, 8);
      ns += __shfl_xor(ns, 8);
      cpk += __shfl_xor(cpk, 8);
      if (l16 < 8) {
        f32x4 v = {ps, ns, cpk, 0.f};
        red4[(wc * BM + lrl) * 8 + l16] = v;
      }
    }
  }
  __syncthreads();
  if (tid < BM) {
    f32x4 s = {0.f, 0.f, 0.f, 0.f};
#pragma unroll
    for (int c2 = 0; c2 < 2; ++c2)
#pragma unroll
      for (int k = 0; k < 8; ++k)  // (k+tid)&7: lanes sweep all 32 banks
        s += red4[(c2 * BM + tid) * 8 + ((k + tid) & 7)];
    float nc = floorf(s[2] * (1.0f / 512.0f));
    float pc = s[2] - 512.f * nc;
    f32x4 o = {s[0], pc, s[1], nc};
    ((f32x4*)part)[(size_t)(rowBase + tid) * npart + jp] = o;  // [row][jp]
  }
}

// ---------- kernel 2b: generic GEMM (fallback for other shapes) ------------
__global__ __launch_bounds__(256)
void gemm_generic_kernel(const unsigned short* __restrict__ refbf,
                         const float* __restrict__ sqb,
                         const int* __restrict__ reflab,
                         float* __restrict__ part,
                         int Dn, int mtiles, int ntiles) {
  __shared__ unsigned short As[BM * BK];
  __shared__ unsigned short Bs[BN * BK];
  __shared__ f32x4 redbuf4[2 * BM];

  int bid = blockIdx.x;
  int it = bid % mtiles, jt = bid / mtiles;
  int rowBase = it * BM, colBase = jt * BN;
  int tid = threadIdx.x, lane = tid & 63, w = tid >> 6;
  int wr = w >> 1, wc = w & 1;
  int l16 = lane & 15, quad = lane >> 4;
  int lrow = lane >> 2, lk = lane & 3;
  size_t rowB = (size_t)Dn * 2;
  int r0 = w * 32 + lrow;
  int ca = (lk - (r0 >> 1)) & 3;
  const char* gA0 = (const char*)refbf + (size_t)(rowBase + r0) * rowB + ca * 16;
  const char* gA1 = gA0 + 16 * rowB;
  const char* gB0 = (const char*)refbf + (size_t)(colBase + r0) * rowB + ca * 16;
  const char* gB1 = gB0 + 16 * rowB;
  char* lA = (char*)As + w * 2048;
  char* lB = (char*)Bs + w * 2048;

  f32x4 acc[4][4] = {};
  for (int k0 = 0; k0 < Dn; k0 += BK) {
    int koff = k0 * 2;
    GLOAD16(gA0 + koff, lA);
    GLOAD16(gA1 + koff, lA + 1024);
    GLOAD16(gB0 + koff, lB);
    GLOAD16(gB1 + koff, lB + 1024);
    __syncthreads();
    short8 af[4], bfr[4];
#pragma unroll
    for (int mi = 0; mi < 4; ++mi) {
      int row = wr * 64 + mi * 16 + l16;
      af[mi] = *(const short8*)&As[row * BK + ((quad + (row >> 1)) & 3) * 8];
    }
#pragma unroll
    for (int ni = 0; ni < 4; ++ni) {
      int row = wc * 64 + ni * 16 + l16;
      bfr[ni] = *(const short8*)&Bs[row * BK + ((quad + (row >> 1)) & 3) * 8];
    }
#pragma unroll
    for (int mi = 0; mi < 4; ++mi)
#pragma unroll
      for (int ni = 0; ni < 4; ++ni)
        acc[mi][ni] = __builtin_amdgcn_mfma_f32_16x16x32_bf16(
            af[mi], bfr[ni], acc[mi][ni], 0, 0, 0);
    __syncthreads();
  }

  float sqc[4];
  int labc[4];
#pragma unroll
  for (int ni = 0; ni < 4; ++ni) {
    int gcol = colBase + wc * 64 + ni * 16 + l16;
    sqc[ni] = sqb[gcol];
    labc[ni] = reflab[gcol];
  }
#pragma unroll
  for (int mi = 0; mi < 4; ++mi) {
    int lr0 = wr * 64 + mi * 16 + quad * 4;
#pragma unroll
    for (int r = 0; r < 4; ++r) {
      int lrl = lr0 + r;
      int grow = rowBase + lrl;
      float sqr = sqb[grow];
      int labr = reflab[grow];
      float ps = 0.f, pc = 0.f, ns = 0.f, nc = 0.f;
#pragma unroll
      for (int ni = 0; ni < 4; ++ni) {
        int gcol = colBase + wc * 64 + ni * 16 + l16;
        float dist = fmaxf(sqr + sqc[ni] - 2.0f * acc[mi][ni][r], 0.f);
        bool self = (gcol == grow);
        bool same = (labc[ni] == labr);
        if (same && !self && dist > 0.f) { ps += dist; pc += 1.f; }
        if (!same && !self && dist < 1.f) { ns += 1.f - dist; nc += 1.f; }
      }
#pragma unroll
      for (int off = 8; off; off >>= 1) {
        ps += __shfl_xor(ps, off);
        pc += __shfl_xor(pc, off);
        ns += __shfl_xor(ns, off);
        nc += __shfl_xor(nc, off);
      }
      if (l16 == 0) {
        f32x4 v = {ps, pc, ns, nc};
        redbuf4[wc * BM + lrl] = v;
      }
    }
  }
  __syncthreads();
  if (tid < BM) {
    f32x4 s = redbuf4[tid] + redbuf4[BM + tid];
    ((f32x4*)part)[(size_t)(rowBase + tid) * ntiles + jt] = s;
  }
}

// ---------- kernel 3: per-row fold + global sum (atomic + ticket) ----------
__global__ __launch_bounds__(256)
void reduce_final_kernel(const float* __restrict__ part,
                         float* __restrict__ facc, int* __restrict__ fcnt,
                         float* __restrict__ out, int Bn, int npart) {
  __shared__ float rsum[4];
  int tid = threadIdx.x, w = tid >> 6, lane = tid & 63;
  int row = blockIdx.x * 4 + w;
  const f32x4* part4 = (const f32x4*)part;
  float rl = 0.f;
  if (row < Bn) {
    f32x4 a = {0.f, 0.f, 0.f, 0.f};
    for (int j = lane; j < npart; j += 64)
      a += part4[(size_t)row * npart + j];
#pragma unroll
    for (int off = 32; off; off >>= 1) {
      a[0] += __shfl_xor(a[0], off);
      a[1] += __shfl_xor(a[1], off);
      a[2] += __shfl_xor(a[2], off);
      a[3] += __shfl_xor(a[3], off);
    }
    rl = a[0] / (a[1] + 1e-6f) + a[2] / (a[3] + 1e-6f);
  }
  if (lane == 0) rsum[w] = rl;
  __syncthreads();
  if (tid == 0) {
    float bs = rsum[0] + rsum[1] + rsum[2] + rsum[3];
    atomicAdd(facc, bs);
    __threadfence();
    int old = atomicAdd(fcnt, 1);
    if (old == (int)gridDim.x - 1) {
      __threadfence();
      float tot = atomicAdd(facc, 0.f);
      out[0] = tot / (float)Bn;
    }
  }
}

// ---------- host ----------
extern "C" void kernel_launch(void* const* d_in, const int* in_sizes, int n_in,
                              void* d_out, int out_size, void* d_ws, size_t ws_size,
                              hipStream_t stream) {
  const float* emb     = (const float*)d_in[0];
  const int*   labels  = (const int*)d_in[1];
  const float* emb_mem = (const float*)d_in[2];
  const int*   lbl_mem = (const int*)d_in[3];
  // d_in[4] (add_to_mem) does not affect the returned loss.

  int Bn = in_sizes[1];
  int Dn = in_sizes[0] / Bn;
  int Rn = in_sizes[3];
  int Mn = Bn + Rn;
  int mtiles = Bn / BM, ntiles = Mn / BN;

  char* ws = (char*)d_ws;
  unsigned short* refbf = (unsigned short*)ws;                 // Mn*Dn bf16
  size_t off = (size_t)Mn * Dn * 2;
  float* sqb    = (float*)(ws + off);                          // Mn
  int*   reflab = (int*)(ws + off + (size_t)Mn * 4);           // Mn
  float* part   = (float*)(ws + off + (size_t)Mn * 8);         // Bn*ntiles*4
  float* facc   = part + (size_t)Bn * ntiles * 4;              // 1
  int*   fcnt   = (int*)(facc + 1);                            // 1

  prep2_kernel<<<(Mn + 3) / 4, 256, 0, stream>>>(
      emb, labels, emb_mem, lbl_mem, refbf, sqb, reflab, facc, fcnt, Bn, Dn, Mn);

  bool fast = (Dn == 512 && mtiles == 8 && ntiles == 256);
  if (fast) {
    gemm512x2db_kernel<<<1024, 256, 0, stream>>>(refbf, sqb, reflab, part);
    reduce_final_kernel<<<(Bn + 3) / 4, 256, 0, stream>>>(
        part, facc, fcnt, (float*)d_out, Bn, 128);
  } else {
    gemm_generic_kernel<<<mtiles * ntiles, 256, 0, stream>>>(
        refbf, sqb, reflab, part, Dn, mtiles, ntiles);
    reduce_final_kernel<<<(Bn + 3) / 4, 256, 0, stream>>>(
        part, facc, fcnt, (float*)d_out, Bn, ntiles);
  }
}

// Round 11
// 158.367 us; speedup vs baseline: 1.0240x; 1.0240x over previous
//
#include <hip/hip_runtime.h>
#include <hip/hip_fp8.h>

typedef __attribute__((ext_vector_type(8))) short short8;
typedef __attribute__((ext_vector_type(4))) float f32x4;

// async global->LDS, 16B per lane, dest = wave-uniform base + lane*16
#define GLOAD16(g, l)                                                        \
  __builtin_amdgcn_global_load_lds(                                          \
      (const __attribute__((address_space(1))) unsigned int*)(g),            \
      (__attribute__((address_space(3))) unsigned int*)(l), 16, 0, 0)

__device__ __forceinline__ unsigned short f2bf(float f) {
  union { float f; unsigned int u; } v;
  v.f = f;
  unsigned int u = v.u;
  u += 0x7FFFu + ((u >> 16) & 1u);  // round-to-nearest-even
  return (unsigned short)(u >> 16);
}

__device__ __forceinline__ short8 pack8(float4 a, float4 b) {
  short8 r;
  r[0] = (short)f2bf(a.x); r[1] = (short)f2bf(a.y);
  r[2] = (short)f2bf(a.z); r[3] = (short)f2bf(a.w);
  r[4] = (short)f2bf(b.x); r[5] = (short)f2bf(b.y);
  r[6] = (short)f2bf(b.z); r[7] = (short)f2bf(b.w);
  return r;
}

__device__ __forceinline__ unsigned char f2e4m3(float x) {
  __hip_fp8_e4m3 t(x);  // OCP e4m3fn, HW cvt on gfx950
  return *reinterpret_cast<unsigned char*>(&t);
}

#define BM 128
#define BN 128
#define BK 32

// ---------- kernel 1a: prep for fp8 fast path (fp32 -> e4m3 + norms) -------
__global__ __launch_bounds__(256)
void prep_fp8_kernel(const float* __restrict__ emb, const int* __restrict__ labels,
                     const float* __restrict__ emb_mem, const int* __restrict__ lbl_mem,
                     unsigned char* __restrict__ refq, float* __restrict__ sqb,
                     int* __restrict__ reflab, float* __restrict__ facc,
                     int* __restrict__ fcnt, int Bn, int Dn, int Mn) {
  if (blockIdx.x == 0 && threadIdx.x == 0) { *facc = 0.f; *fcnt = 0; }
  int wid = threadIdx.x >> 6, lane = threadIdx.x & 63;
  int row = blockIdx.x * 4 + wid;
  if (row >= Mn) return;
  const float* src = (row < Bn) ? (emb + (size_t)row * Dn)
                                : (emb_mem + (size_t)(row - Bn) * Dn);
  unsigned char* dst = refq + (size_t)row * Dn;
  float s = 0.f;
  for (int c0 = lane * 8; c0 < Dn; c0 += 64 * 8) {
    float4 v0 = ((const float4*)(src + c0))[0];
    float4 v1 = ((const float4*)(src + c0))[1];
    s += v0.x * v0.x + v0.y * v0.y + v0.z * v0.z + v0.w * v0.w;
    s += v1.x * v1.x + v1.y * v1.y + v1.z * v1.z + v1.w * v1.w;
    unsigned long long p =
        (unsigned long long)f2e4m3(v0.x)        |
        ((unsigned long long)f2e4m3(v0.y) << 8) |
        ((unsigned long long)f2e4m3(v0.z) << 16)|
        ((unsigned long long)f2e4m3(v0.w) << 24)|
        ((unsigned long long)f2e4m3(v1.x) << 32)|
        ((unsigned long long)f2e4m3(v1.y) << 40)|
        ((unsigned long long)f2e4m3(v1.z) << 48)|
        ((unsigned long long)f2e4m3(v1.w) << 56);
    *(unsigned long long*)(dst + c0) = p;
  }
#pragma unroll
  for (int off = 32; off; off >>= 1) s += __shfl_xor(s, off);
  if (lane == 0) {
    sqb[row] = s;
    reflab[row] = (row < Bn) ? labels[row] : lbl_mem[row - Bn];
  }
}

// ---------- kernel 2a: fp8 GEMM 128x256, r8 two-barrier structure ----------
// BK=32 fp8 = 32B/row: A-tile 4KB, B-tile 8KB (half of r8's bf16 bytes).
// Per wave per iter: 3 GLOAD16 (was 6), 12 ds_read_b64 (was b128), 32 MFMAs.
// Chunk rotation cL=(lane&1)^((lane>>3)&1) makes b64 reads <=2-way (free).
__global__ __launch_bounds__(256, 2)
void gemm512x2f8_kernel(const unsigned char* __restrict__ refq,
                        const float* __restrict__ sqb,
                        const int* __restrict__ reflab,
                        float* __restrict__ part) {
  // 32KB: staging uses [As 4K | Bs 8K]; epilogue red4 aliases all 32KB
  __shared__ __align__(16) char smem[32768];
  char* As = smem;
  char* Bs = smem + 4096;
  f32x4* red4 = (f32x4*)smem;  // [2][128][8] f32x4

  const int npart = 128;               // j-pairs
  int bid = blockIdx.x;                // 1024 blocks
  int c = bid & 7, g = bid >> 3;       // XCD-sliced (validated r3/r5)
  int jp = c * 16 + (g >> 3);          // j-pair index [0,128)
  int it = g & 7;
  int rowBase = it * BM, colBase = jp * 256;

  int tid = threadIdx.x, lane = tid & 63, w = tid >> 6;
  int wr = w >> 1, wc = w & 1;         // 2x2 waves; each 64 rows x 128 cols
  int l16 = lane & 15, quad = lane >> 4;

  // staging: 2 lanes per 32B tile-row; physical chunk (lane&1) holds logical
  // chunk cL = (lane&1) ^ ((row>>2)&1) -> read-side bank spread <=2-way
  int lrow = lane >> 1;
  int cL = (lane & 1) ^ ((lane >> 3) & 1);
  const char* gA0 = (const char*)refq + (size_t)(rowBase + w * 32 + lrow) * 512 + cL * 16;
  const char* gB0 = (const char*)refq + (size_t)(colBase + w * 64 + lrow) * 512 + cL * 16;
  const char* gB1 = gB0 + 32 * 512;
  char* lA = As + w * 1024;
  char* lB = Bs + w * 2048;

  f32x4 acc[4][8] = {};
  for (int kk = 0; kk < 16; ++kk) {
    int ko = kk * 32;
    GLOAD16(gA0 + ko, lA);
    GLOAD16(gB0 + ko, lB);
    GLOAD16(gB1 + ko, lB + 1024);
    __syncthreads();
    long af[4], bfr[8];
#pragma unroll
    for (int mi = 0; mi < 4; ++mi) {
      int row = wr * 64 + mi * 16 + l16;
      int off = row * 32 + ((((quad >> 1) ^ ((row >> 2) & 1)) << 4)) + (quad & 1) * 8;
      af[mi] = *(const long*)(As + off);
    }
#pragma unroll
    for (int ni = 0; ni < 8; ++ni) {
      int row = wc * 128 + ni * 16 + l16;
      int off = row * 32 + ((((quad >> 1) ^ ((row >> 2) & 1)) << 4)) + (quad & 1) * 8;
      bfr[ni] = *(const long*)(Bs + off);
    }
#pragma unroll
    for (int mi = 0; mi < 4; ++mi)
#pragma unroll
      for (int ni = 0; ni < 8; ++ni)
        acc[mi][ni] = __builtin_amdgcn_mfma_f32_16x16x32_fp8_fp8(
            af[mi], bfr[ni], acc[mi][ni], 0, 0, 0);
    __syncthreads();
  }

  // ---- epilogue (r8-validated): packed counters, 1 shfl, LDS fold --------
  float sqc[8];
  int labc[8];
#pragma unroll
  for (int ni = 0; ni < 8; ++ni) {
    int gcol = colBase + wc * 128 + ni * 16 + l16;
    sqc[ni] = sqb[gcol];
    labc[ni] = reflab[gcol];
  }
#pragma unroll
  for (int mi = 0; mi < 4; ++mi) {
    int lr0 = wr * 64 + mi * 16 + quad * 4;
#pragma unroll
    for (int r = 0; r < 4; ++r) {
      int lrl = lr0 + r;
      int grow = rowBase + lrl;
      float sqr = sqb[grow];
      int labr = reflab[grow];
      float ps = 0.f, ns = 0.f, cpk = 0.f;  // cpk = pos_cnt + 512*neg_cnt
#pragma unroll
      for (int ni = 0; ni < 8; ++ni) {
        int gcol = colBase + wc * 128 + ni * 16 + l16;
        float dist = fmaxf(sqr + sqc[ni] - 2.0f * acc[mi][ni][r], 0.f);
        bool self = (gcol == grow);  // idx_ref[j]!=i reduces to j!=i
        bool same = (labc[ni] == labr);
        if (same && !self && dist > 0.f) { ps += dist; cpk += 1.f; }
        if (!same && !self && dist < 1.f) { ns += 1.f - dist; cpk += 512.f; }
      }
      ps += __shfl_xor(ps, 8);
      ns += __shfl_xor(ns, 8);
      cpk += __shfl_xor(cpk, 8);
      if (l16 < 8) {
        f32x4 v = {ps, ns, cpk, 0.f};
        red4[(wc * BM + lrl) * 8 + l16] = v;
      }
    }
  }
  __syncthreads();
  if (tid < BM) {
    f32x4 s = {0.f, 0.f, 0.f, 0.f};
#pragma unroll
    for (int c2 = 0; c2 < 2; ++c2)
#pragma unroll
      for (int k = 0; k < 8; ++k)  // (k+tid)&7: lanes sweep all 32 banks
        s += red4[(c2 * BM + tid) * 8 + ((k + tid) & 7)];
    float nc = floorf(s[2] * (1.0f / 512.0f));
    float pc = s[2] - 512.f * nc;
    f32x4 o = {s[0], pc, s[1], nc};
    ((f32x4*)part)[(size_t)(rowBase + tid) * npart + jp] = o;  // [row][jp]
  }
}

// ---------- fallback path (generic shapes): bf16 prep + generic GEMM -------
__global__ __launch_bounds__(256)
void prep2_kernel(const float* __restrict__ emb, const int* __restrict__ labels,
                  const float* __restrict__ emb_mem, const int* __restrict__ lbl_mem,
                  unsigned short* __restrict__ refbf, float* __restrict__ sqb,
                  int* __restrict__ reflab, float* __restrict__ facc,
                  int* __restrict__ fcnt, int Bn, int Dn, int Mn) {
  if (blockIdx.x == 0 && threadIdx.x == 0) { *facc = 0.f; *fcnt = 0; }
  int wid = threadIdx.x >> 6, lane = threadIdx.x & 63;
  int row = blockIdx.x * 4 + wid;
  if (row >= Mn) return;
  const float* src = (row < Bn) ? (emb + (size_t)row * Dn)
                                : (emb_mem + (size_t)(row - Bn) * Dn);
  unsigned short* dst = refbf + (size_t)row * Dn;
  float s = 0.f;
  for (int c0 = lane * 8; c0 < Dn; c0 += 64 * 8) {
    float4 v0 = ((const float4*)(src + c0))[0];
    float4 v1 = ((const float4*)(src + c0))[1];
    s += v0.x * v0.x + v0.y * v0.y + v0.z * v0.z + v0.w * v0.w;
    s += v1.x * v1.x + v1.y * v1.y + v1.z * v1.z + v1.w * v1.w;
    *(short8*)(dst + c0) = pack8(v0, v1);
  }
#pragma unroll
  for (int off = 32; off; off >>= 1) s += __shfl_xor(s, off);
  if (lane == 0) {
    sqb[row] = s;
    reflab[row] = (row < Bn) ? labels[row] : lbl_mem[row - Bn];
  }
}

__global__ __launch_bounds__(256)
void gemm_generic_kernel(const unsigned short* __restrict__ refbf,
                         const float* __restrict__ sqb,
                         const int* __restrict__ reflab,
                         float* __restrict__ part,
                         int Dn, int mtiles, int ntiles) {
  __shared__ unsigned short As[BM * BK];
  __shared__ unsigned short Bs[BN * BK];
  __shared__ f32x4 redbuf4[2 * BM];

  int bid = blockIdx.x;
  int it = bid % mtiles, jt = bid / mtiles;
  int rowBase = it * BM, colBase = jt * BN;
  int tid = threadIdx.x, lane = tid & 63, w = tid >> 6;
  int wr = w >> 1, wc = w & 1;
  int l16 = lane & 15, quad = lane >> 4;
  int lrow = lane >> 2, lk = lane & 3;
  size_t rowB = (size_t)Dn * 2;
  int r0 = w * 32 + lrow;
  int ca = (lk - (r0 >> 1)) & 3;
  const char* gA0 = (const char*)refbf + (size_t)(rowBase + r0) * rowB + ca * 16;
  const char* gA1 = gA0 + 16 * rowB;
  const char* gB0 = (const char*)refbf + (size_t)(colBase + r0) * rowB + ca * 16;
  const char* gB1 = gB0 + 16 * rowB;
  char* lA = (char*)As + w * 2048;
  char* lB = (char*)Bs + w * 2048;

  f32x4 acc[4][4] = {};
  for (int k0 = 0; k0 < Dn; k0 += BK) {
    int koff = k0 * 2;
    GLOAD16(gA0 + koff, lA);
    GLOAD16(gA1 + koff, lA + 1024);
    GLOAD16(gB0 + koff, lB);
    GLOAD16(gB1 + koff, lB + 1024);
    __syncthreads();
    short8 af[4], bfr[4];
#pragma unroll
    for (int mi = 0; mi < 4; ++mi) {
      int row = wr * 64 + mi * 16 + l16;
      af[mi] = *(const short8*)&As[row * BK + ((quad + (row >> 1)) & 3) * 8];
    }
#pragma unroll
    for (int ni = 0; ni < 4; ++ni) {
      int row = wc * 64 + ni * 16 + l16;
      bfr[ni] = *(const short8*)&Bs[row * BK + ((quad + (row >> 1)) & 3) * 8];
    }
#pragma unroll
    for (int mi = 0; mi < 4; ++mi)
#pragma unroll
      for (int ni = 0; ni < 4; ++ni)
        acc[mi][ni] = __builtin_amdgcn_mfma_f32_16x16x32_bf16(
            af[mi], bfr[ni], acc[mi][ni], 0, 0, 0);
    __syncthreads();
  }

  float sqc[4];
  int labc[4];
#pragma unroll
  for (int ni = 0; ni < 4; ++ni) {
    int gcol = colBase + wc * 64 + ni * 16 + l16;
    sqc[ni] = sqb[gcol];
    labc[ni] = reflab[gcol];
  }
#pragma unroll
  for (int mi = 0; mi < 4; ++mi) {
    int lr0 = wr * 64 + mi * 16 + quad * 4;
#pragma unroll
    for (int r = 0; r < 4; ++r) {
      int lrl = lr0 + r;
      int grow = rowBase + lrl;
      float sqr = sqb[grow];
      int labr = reflab[grow];
      float ps = 0.f, pc = 0.f, ns = 0.f, nc = 0.f;
#pragma unroll
      for (int ni = 0; ni < 4; ++ni) {
        int gcol = colBase + wc * 64 + ni * 16 + l16;
        float dist = fmaxf(sqr + sqc[ni] - 2.0f * acc[mi][ni][r], 0.f);
        bool self = (gcol == grow);
        bool same = (labc[ni] == labr);
        if (same && !self && dist > 0.f) { ps += dist; pc += 1.f; }
        if (!same && !self && dist < 1.f) { ns += 1.f - dist; nc += 1.f; }
      }
#pragma unroll
      for (int off = 8; off; off >>= 1) {
        ps += __shfl_xor(ps, off);
        pc += __shfl_xor(pc, off);
        ns += __shfl_xor(ns, off);
        nc += __shfl_xor(nc, off);
      }
      if (l16 == 0) {
        f32x4 v = {ps, pc, ns, nc};
        redbuf4[wc * BM + lrl] = v;
      }
    }
  }
  __syncthreads();
  if (tid < BM) {
    f32x4 s = redbuf4[tid] + redbuf4[BM + tid];
    ((f32x4*)part)[(size_t)(rowBase + tid) * ntiles + jt] = s;
  }
}

// ---------- kernel 3: per-row fold + global sum (atomic + ticket) ----------
__global__ __launch_bounds__(256)
void reduce_final_kernel(const float* __restrict__ part,
                         float* __restrict__ facc, int* __restrict__ fcnt,
                         float* __restrict__ out, int Bn, int npart) {
  __shared__ float rsum[4];
  int tid = threadIdx.x, w = tid >> 6, lane = tid & 63;
  int row = blockIdx.x * 4 + w;
  const f32x4* part4 = (const f32x4*)part;
  float rl = 0.f;
  if (row < Bn) {
    f32x4 a = {0.f, 0.f, 0.f, 0.f};
    for (int j = lane; j < npart; j += 64)
      a += part4[(size_t)row * npart + j];
#pragma unroll
    for (int off = 32; off; off >>= 1) {
      a[0] += __shfl_xor(a[0], off);
      a[1] += __shfl_xor(a[1], off);
      a[2] += __shfl_xor(a[2], off);
      a[3] += __shfl_xor(a[3], off);
    }
    rl = a[0] / (a[1] + 1e-6f) + a[2] / (a[3] + 1e-6f);
  }
  if (lane == 0) rsum[w] = rl;
  __syncthreads();
  if (tid == 0) {
    float bs = rsum[0] + rsum[1] + rsum[2] + rsum[3];
    atomicAdd(facc, bs);
    __threadfence();
    int old = atomicAdd(fcnt, 1);
    if (old == (int)gridDim.x - 1) {
      __threadfence();
      float tot = atomicAdd(facc, 0.f);
      out[0] = tot / (float)Bn;
    }
  }
}

// ---------- host ----------
extern "C" void kernel_launch(void* const* d_in, const int* in_sizes, int n_in,
                              void* d_out, int out_size, void* d_ws, size_t ws_size,
                              hipStream_t stream) {
  const float* emb     = (const float*)d_in[0];
  const int*   labels  = (const int*)d_in[1];
  const float* emb_mem = (const float*)d_in[2];
  const int*   lbl_mem = (const int*)d_in[3];
  // d_in[4] (add_to_mem) does not affect the returned loss.

  int Bn = in_sizes[1];
  int Dn = in_sizes[0] / Bn;
  int Rn = in_sizes[3];
  int Mn = Bn + Rn;
  int mtiles = Bn / BM, ntiles = Mn / BN;

  char* ws = (char*)d_ws;
  unsigned char*  refq  = (unsigned char*)ws;                  // Mn*Dn fp8 (fast)
  unsigned short* refbf = (unsigned short*)ws;                 // Mn*Dn bf16 (generic)
  size_t off = (size_t)Mn * Dn * 2;                            // sized for bf16
  float* sqb    = (float*)(ws + off);                          // Mn
  int*   reflab = (int*)(ws + off + (size_t)Mn * 4);           // Mn
  float* part   = (float*)(ws + off + (size_t)Mn * 8);         // Bn*ntiles*4
  float* facc   = part + (size_t)Bn * ntiles * 4;              // 1
  int*   fcnt   = (int*)(facc + 1);                            // 1

  bool fast = (Dn == 512 && mtiles == 8 && ntiles == 256);
  if (fast) {
    prep_fp8_kernel<<<(Mn + 3) / 4, 256, 0, stream>>>(
        emb, labels, emb_mem, lbl_mem, refq, sqb, reflab, facc, fcnt, Bn, Dn, Mn);
    gemm512x2f8_kernel<<<1024, 256, 0, stream>>>(refq, sqb, reflab, part);
    reduce_final_kernel<<<(Bn + 3) / 4, 256, 0, stream>>>(
        part, facc, fcnt, (float*)d_out, Bn, 128);
  } else {
    prep2_kernel<<<(Mn + 3) / 4, 256, 0, stream>>>(
        emb, labels, emb_mem, lbl_mem, refbf, sqb, reflab, facc, fcnt, Bn, Dn, Mn);
    gemm_generic_kernel<<<mtiles * ntiles, 256, 0, stream>>>(
        refbf, sqb, reflab, part, Dn, mtiles, ntiles);
    reduce_final_kernel<<<(Bn + 3) / 4, 256, 0, stream>>>(
        part, facc, fcnt, (float*)d_out, Bn, ntiles);
  }
}